// Round 13
// baseline (67.523 us; speedup 1.0000x reference)
//
#include <hip/hip_runtime.h>

// DETR-style post-process: softmax scores/labels + box scale + per-image greedy NMS.
// Outputs (flat f32, concatenated): scores[B*Q] | labels[B*Q] | boxes[B*Q*4] | keep[B*Q]
//
// Pipeline (3 graph nodes):
//  k_score_box : per-(b,q) wave softmax/argmax + box conversion + sort key (HBM-bound)
//  k_rank      : counting-rank, register/readlane key scan (VALU, ~4-5us); zeroes done[]
//  k_mask_scan : mask tiles (blocks y=0..8) + per-image scan block (y=9) with
//                agent-scope release/acquire handshake -> one node, one less boundary

constexpr int kB  = 32;
constexpr int kQ  = 1024;
constexpr int kNC = 256;
constexpr int kBQ = kB * kQ;

typedef unsigned long long u64;
typedef unsigned int u32;

// IoU > 0.5 with bit-identical result to fdiv_rn(inter,u) > 0.5f, branch-free:
// RN32(inter/u) > 0.5 <=> real inter/u > 0.5+2^-25 (midpoint; tie rounds to even
// = 0.5; exact equality impossible - needs 25-bit mantissa). (double)u*(0.5+2^-25)
// is EXACT (24b x 25b = 49b < 53b), so this is an exact real-number compare.
__device__ __forceinline__ bool iou_gt(const float4& a, float aa,
                                       const float4& b, float ba) {
  float lx = fmaxf(a.x, b.x);
  float ly = fmaxf(a.y, b.y);
  float rx = fminf(a.z, b.z);
  float ry = fminf(a.w, b.w);
  float w  = fmaxf(__fsub_rn(rx, lx), 0.0f);
  float h  = fmaxf(__fsub_rn(ry, ly), 0.0f);
  float inter = __fmul_rn(w, h);
  float u  = fmaxf(__fsub_rn(__fadd_rn(aa, ba), inter), 1e-9f);
  return (double)inter > (double)u * 0.50000002980232238769531250;
}

// One wave (64 lanes) per (b,q): 256 logits -> softmax score/label; box cxcywh->xyxy*scale.
// Also emits the u64 stable-descending sort key for k_rank.
__global__ void k_score_box(const float* __restrict__ logits,
                            const float* __restrict__ pboxes,
                            const int* __restrict__ ts,
                            float* __restrict__ out,
                            u64* __restrict__ keys) {
  int gw   = (int)((blockIdx.x * blockDim.x + threadIdx.x) >> 6);
  int lane = (int)(threadIdx.x & 63);
  if (gw >= kBQ) return;

  float4 v = reinterpret_cast<const float4*>(logits)[gw * (kNC / 4) + lane];

  // foreground (first 255 classes) max + argmax, first-occurrence tie-break
  float fw = (lane == 63) ? -INFINITY : v.w;
  float fm = v.x; int fi = lane * 4;
  if (v.y > fm) { fm = v.y; fi = lane * 4 + 1; }
  if (v.z > fm) { fm = v.z; fi = lane * 4 + 2; }
  if (fw  > fm) { fm = fw;  fi = lane * 4 + 3; }
  for (int off = 32; off > 0; off >>= 1) {
    float om = __shfl_xor(fm, off, 64);
    int   oi = __shfl_xor(fi, off, 64);
    if (om > fm || (om == fm && oi < fi)) { fm = om; fi = oi; }
  }

  float last = __shfl(v.w, 63, 64);     // logit of class 255 (bg)
  float m = fmaxf(fm, last);            // max over all 256 (exact)

  float s = expf(v.x - m) + expf(v.y - m) + expf(v.z - m) + expf(v.w - m);
  for (int off = 32; off > 0; off >>= 1) s += __shfl_xor(s, off, 64);

  if (lane == 0) {
    float sc = expf(fm - m) / s;
    out[gw]       = sc;
    out[kBQ + gw] = (float)fi;
    keys[gw] = ((u64)(~__float_as_uint(sc)) << 32) | (u32)(gw & (kQ - 1));

    float4 pb = reinterpret_cast<const float4*>(pboxes)[gw];
    int bi = gw >> 10;
    float ih = (float)ts[bi * 2 + 0];
    float iw = (float)ts[bi * 2 + 1];
    float hw = __fmul_rn(0.5f, pb.z);
    float hh = __fmul_rn(0.5f, pb.w);
    float x0 = __fmul_rn(__fsub_rn(pb.x, hw), iw);
    float y0 = __fmul_rn(__fsub_rn(pb.y, hh), ih);
    float x1 = __fmul_rn(__fadd_rn(pb.x, hw), iw);
    float y1 = __fmul_rn(__fadd_rn(pb.y, hh), ih);
    reinterpret_cast<float4*>(out + 2 * kBQ)[gw] = make_float4(x0, y0, x1, y1);
  }
}

// Counting rank: rank_j = #{k : key_k < key_j}. Keys staged once in LDS, then each
// wave pulls 128 keys/batch into registers (ds_read_b128) and compares via
// v_readlane broadcasts -> pure VALU, no DS-pipe serialization (R11/R12 lesson).
// Exactly reproduces stable argsort(-scores). grid (32,4) x 256. Also zeroes done[].
__global__ void __launch_bounds__(256) k_rank(const u64* __restrict__ keys,
                                              const float* __restrict__ out,
                                              u32* __restrict__ order,
                                              float4* __restrict__ sbox,
                                              float* __restrict__ sarea,
                                              u32* __restrict__ done) {
  __shared__ __align__(16) u64 ks[kQ];
  const int b = (int)blockIdx.x, sb = (int)blockIdx.y, tid = (int)threadIdx.x;
  if (sb == 0 && tid == 0) done[b] = 0;             // handshake reset for k_mask_scan

  for (int t = tid; t < kQ; t += 256) ks[t] = keys[b * kQ + t];
  __syncthreads();

  const int lane = tid & 63;
  const int j = sb * 256 + tid;
  const u64 kj = ks[j];
  int cnt = 0;
  const ulonglong2* ks2 = reinterpret_cast<const ulonglong2*>(ks);
  for (int bi = 0; bi < 8; ++bi) {
    ulonglong2 kk = ks2[bi * 64 + lane];            // 128 keys/wave-batch, 1 b128/lane
    int a0lo = (int)(u32)kk.x, a0hi = (int)(u32)(kk.x >> 32);
    int a1lo = (int)(u32)kk.y, a1hi = (int)(u32)(kk.y >> 32);
    #pragma unroll 8
    for (int l = 0; l < 64; ++l) {
      u64 k0 = ((u64)(u32)__builtin_amdgcn_readlane(a0hi, l) << 32)
             |  (u64)(u32)__builtin_amdgcn_readlane(a0lo, l);
      u64 k1 = ((u64)(u32)__builtin_amdgcn_readlane(a1hi, l) << 32)
             |  (u64)(u32)__builtin_amdgcn_readlane(a1lo, l);
      cnt += (int)(k0 < kj) + (int)(k1 < kj);
    }
  }

  float4 bx = reinterpret_cast<const float4*>(out + 2 * kBQ)[b * kQ + j];
  order[b * kQ + cnt] = (u32)j;
  sbox[b * kQ + cnt]  = bx;
  sarea[b * kQ + cnt] = __fmul_rn(__fsub_rn(bx.z, bx.x), __fsub_rn(bx.w, bx.y));
}

// Merged mask+scan, one node. grid (32, 10) x 1024.
// Blocks y=0..8: 16 waves, one 64x64 tri-tile each (r = y*16+wv, valid r<136);
//   after stores: __syncthreads + agent-RELEASE fetch_add(done[b]).
// Block y=9: spin (ACQUIRE) until done[b]==9, then the proven pipelined
//   fixpoint scan (byte-identical to round-10 k_scan body).
__global__ void __launch_bounds__(1024) k_mask_scan(const float4* __restrict__ sbox,
                                                    const float* __restrict__ sarea,
                                                    u64* __restrict__ maskT,
                                                    const u32* __restrict__ order,
                                                    u32* __restrict__ done,
                                                    float* __restrict__ out) {
  const int b = (int)blockIdx.x, y = (int)blockIdx.y;
  const int tid = (int)threadIdx.x, lane = tid & 63, wv = tid >> 6;

  __shared__ float4 iboxS[16][64];
  __shared__ float  iareaS[16][64];
  __shared__ u64 aliveS[16];
  __shared__ u32 doneS;

  if (y < 9) {
    // ---------------- mask tiles ----------------
    const int r = y * 16 + wv;                      // tile id, one per wave
    if (r < 136) {
      int jb = (int)((sqrtf((float)(8 * r + 1)) - 1.0f) * 0.5f);
      while ((jb + 1) * (jb + 2) / 2 <= r) ++jb;
      while (jb * (jb + 1) / 2 > r) --jb;
      const int c = r - jb * (jb + 1) / 2;

      iboxS[wv][lane]  = sbox[b * kQ + c * 64 + lane];
      iareaS[wv][lane] = sarea[b * kQ + c * 64 + lane];
      // wave-private LDS slice: in-wave ds ordering suffices, no block barrier.

      const int j = jb * 64 + lane;
      const float4 bj = sbox[b * kQ + j];
      const float  aj = sarea[b * kQ + j];

      u32 wlo = 0, whi = 0;
      if (c < jb) {                                 // full tile: every i < j
        #pragma unroll 4
        for (int l = 0; l < 32; ++l)
          wlo |= ((u32)iou_gt(iboxS[wv][l], iareaS[wv][l], bj, aj)) << l;
        #pragma unroll 4
        for (int l = 0; l < 32; ++l)
          whi |= ((u32)iou_gt(iboxS[wv][l + 32], iareaS[wv][l + 32], bj, aj)) << l;
      } else {                                      // diagonal: strict l < lane
        #pragma unroll 4
        for (int l = 0; l < 32; ++l)
          wlo |= ((u32)((l < lane) && iou_gt(iboxS[wv][l], iareaS[wv][l], bj, aj))) << l;
        #pragma unroll 4
        for (int l = 0; l < 32; ++l)
          whi |= ((u32)((l + 32 < lane) && iou_gt(iboxS[wv][l + 32], iareaS[wv][l + 32], bj, aj))) << l;
      }
      maskT[(b * 16 + c) * kQ + j] = ((u64)whi << 32) | wlo;
    }
    __syncthreads();                                // all waves' stores issued
    if (tid == 0)
      __hip_atomic_fetch_add(&done[b], 1u, __ATOMIC_RELEASE, __HIP_MEMORY_SCOPE_AGENT);
    return;
  }

  // ---------------- scan block (y == 9) ----------------
  if (tid == 0) {
    while (__hip_atomic_load(&done[b], __ATOMIC_ACQUIRE, __HIP_MEMORY_SCOPE_AGENT) < 9u)
      __builtin_amdgcn_s_sleep(4);
  }
  __syncthreads();

  const int k = wv;                                 // wave id == chunk id
  const u64* mb = maskT + (size_t)(b * 16) * kQ;
  u64 w[15];
  #pragma unroll
  for (int c = 0; c < 15; ++c)
    w[c] = (c < k) ? mb[c * kQ + k * 64 + lane] : 0ull;
  u64 d = mb[k * kQ + k * 64 + lane];               // diag word (bits i<lane only)
  u32 oj = order[b * kQ + k * 64 + lane];

  if (tid == 0) doneS = 0;
  __syncthreads();

  bool supp = false;
  #pragma unroll
  for (int c = 0; c < 15; ++c) {
    if (c >= k) break;                              // wave-uniform
    u32 dn;
    do {
      dn = __hip_atomic_load(&doneS, __ATOMIC_ACQUIRE, __HIP_MEMORY_SCOPE_WORKGROUP);
    } while ((int)dn <= c);
    supp = supp || ((w[c] & aliveS[c]) != 0ull);
  }

  // layered fixpoint within chunk k
  u64 dead     = __ballot(supp);
  u64 alive    = 0ull;
  u64 resolved = dead;
  for (int it = 0; it < 64 && resolved != ~0ull; ++it) {
    u64 nA = __ballot((d & ~dead) == 0ull) & ~resolved;  // all suppressors dead
    alive    |= nA;
    resolved |= nA;
    u64 nD = __ballot((d & alive) != 0ull) & ~resolved;  // some alive suppressor
    dead     |= nD;
    resolved |= nD;
  }
  if (lane == 0) {
    aliveS[k] = alive;
    __hip_atomic_store(&doneS, (u32)(k + 1), __ATOMIC_RELEASE, __HIP_MEMORY_SCOPE_WORKGROUP);
  }

  out[6 * kBQ + b * kQ + (int)oj] = ((alive >> lane) & 1ull) ? 1.0f : 0.0f;
}

extern "C" void kernel_launch(void* const* d_in, const int* in_sizes, int n_in,
                              void* d_out, int out_size, void* d_ws, size_t ws_size,
                              hipStream_t stream) {
  const float* logits = (const float*)d_in[0];
  const float* pboxes = (const float*)d_in[1];
  const int*   ts     = (const int*)d_in[2];
  float* out = (float*)d_out;

  // ws layout (≈5 MB): maskT 4MB | order 128KB | sbox 512KB | sarea 128KB | keys 256KB | done 128B
  char* ws = (char*)d_ws;
  u64*    maskT = (u64*)ws;
  u32*    order = (u32*)(ws + (4 << 20));
  float4* sbox  = (float4*)(ws + (4 << 20) + (128 << 10));
  float*  sarea = (float*)(ws + (4 << 20) + (640 << 10));
  u64*    keys  = (u64*)(ws + (4 << 20) + (768 << 10));
  u32*    done  = (u32*)(ws + (4 << 20) + (1024 << 10));

  dim3 g1(kBQ / 4), t1(256);
  k_score_box<<<g1, t1, 0, stream>>>(logits, pboxes, ts, out, keys);

  dim3 g2(kB, kQ / 256), t2(256);
  k_rank<<<g2, t2, 0, stream>>>(keys, out, order, sbox, sarea, done);

  dim3 g3(kB, 10), t3(1024);
  k_mask_scan<<<g3, t3, 0, stream>>>(sbox, sarea, maskT, order, done, out);
}